// Round 1
// baseline (2379.955 us; speedup 1.0000x reference)
//
#include <hip/hip_runtime.h>

// Problem: VQ nearest-code search + gather + loss.
// z_real [32,1024,512] f32, z_imag same, embedding [4096,512] f32.
// N=32768 rows, D=512, K=4096.
// Outputs (flat concat, f32): quantized (16777216) | z_imag (16777216) | loss (1).

#define NROWS 32768
#define DDIM  512
#define KCODES 4096
#define TM 64
#define TN 64
#define DK 32

// ------------------------- K1: h[k] = 0.5*||e_k||^2 -------------------------
__global__ void enorm_kernel(const float* __restrict__ E, float* __restrict__ h) {
    const int k = blockIdx.x * 4 + (threadIdx.x >> 6);
    const int lane = threadIdx.x & 63;
    const float* row = E + (size_t)k * DDIM;
    float s = 0.f;
    #pragma unroll
    for (int d = 0; d < DDIM / 64; ++d) {
        float v = row[lane + d * 64];
        s += v * v;
    }
    #pragma unroll
    for (int off = 32; off; off >>= 1) s += __shfl_down(s, off, 64);
    if (lane == 0) h[k] = 0.5f * s;
}

// ------------------- K2: per-row argmin of h[k] - x.e_k ---------------------
// Block: 256 threads (16x16). Block owns TM=64 rows, loops over all K in
// TN=64 tiles; D-loop staged in LDS chunks of DK=32 (transposed layout so the
// inner loop does two ds_read_b128 per d). 4x4 accumulators per thread.
__global__ __launch_bounds__(256) void argmin_kernel(
    const float* __restrict__ X, const float* __restrict__ E,
    const float* __restrict__ h, int* __restrict__ out_idx) {
    // stride TM+4=68 floats keeps float4 reads 16B-aligned (68*4=272 = 17*16)
    __shared__ float As[DK][TM + 4];
    __shared__ float Bs[DK][TN + 4];
    __shared__ float redv[TM][16];
    __shared__ int   redi[TM][16];

    const int t = threadIdx.x;
    const int tx = t & 15;        // k direction
    const int ty = t >> 4;        // row direction
    const int rowBase = blockIdx.x * TM;

    float best[4];
    int   besti[4];
    #pragma unroll
    for (int r = 0; r < 4; ++r) { best[r] = 3.4e38f; besti[r] = 0; }

    for (int kt = 0; kt < KCODES; kt += TN) {
        float c[4][4];
        #pragma unroll
        for (int r = 0; r < 4; ++r)
            #pragma unroll
            for (int j = 0; j < 4; ++j) c[r][j] = 0.f;

        for (int d0 = 0; d0 < DDIM; d0 += DK) {
            __syncthreads();   // protect previous iteration's LDS reads
            // stage 64 rows x 32 d of X and E: 512 float4 each, 2/thread
            #pragma unroll
            for (int i = 0; i < 2; ++i) {
                const int f   = t + i * 256;
                const int row = f >> 3;          // 8 float4 per row-chunk
                const int d4  = (f & 7) << 2;
                float4 v = *(const float4*)(X + (size_t)(rowBase + row) * DDIM + d0 + d4);
                As[d4 + 0][row] = v.x; As[d4 + 1][row] = v.y;
                As[d4 + 2][row] = v.z; As[d4 + 3][row] = v.w;
                float4 w = *(const float4*)(E + (size_t)(kt + row) * DDIM + d0 + d4);
                Bs[d4 + 0][row] = w.x; Bs[d4 + 1][row] = w.y;
                Bs[d4 + 2][row] = w.z; Bs[d4 + 3][row] = w.w;
            }
            __syncthreads();
            #pragma unroll
            for (int d = 0; d < DK; ++d) {
                float4 av = *(const float4*)&As[d][ty * 4];
                float4 bv = *(const float4*)&Bs[d][tx * 4];
                float a[4] = {av.x, av.y, av.z, av.w};
                float b[4] = {bv.x, bv.y, bv.z, bv.w};
                #pragma unroll
                for (int r = 0; r < 4; ++r)
                    #pragma unroll
                    for (int j = 0; j < 4; ++j)
                        c[r][j] += a[r] * b[j];
            }
        }
        // fold in 0.5*||e||^2 and update running argmin (k ascending => strict
        // '<' keeps the lowest index on ties, matching numpy argmin)
        float4 hv = *(const float4*)(h + kt + tx * 4);
        float hj[4] = {hv.x, hv.y, hv.z, hv.w};
        #pragma unroll
        for (int j = 0; j < 4; ++j) {
            const int k = kt + tx * 4 + j;
            #pragma unroll
            for (int r = 0; r < 4; ++r) {
                float s = hj[j] - c[r][j];
                if (s < best[r]) { best[r] = s; besti[r] = k; }
            }
        }
    }

    #pragma unroll
    for (int r = 0; r < 4; ++r) {
        redv[ty * 4 + r][tx] = best[r];
        redi[ty * 4 + r][tx] = besti[r];
    }
    __syncthreads();
    if (t < TM) {
        float m = redv[t][0];
        int  mi = redi[t][0];
        #pragma unroll
        for (int x = 1; x < 16; ++x) {
            float v = redv[t][x];
            int  vi = redi[t][x];
            if (v < m || (v == m && vi < mi)) { m = v; mi = vi; }
        }
        out_idx[rowBase + t] = mi;
    }
}

// ---------- K3: gather quantized, copy z_imag, per-block loss partial -------
__global__ __launch_bounds__(256) void gather_kernel(
    const float* __restrict__ Zr, const float* __restrict__ Zi,
    const float* __restrict__ E, const int* __restrict__ idx,
    float* __restrict__ out, float* __restrict__ partials) {
    const int i = blockIdx.x * 256 + threadIdx.x;   // float4 index
    const size_t base = (size_t)i * 4;
    const int n = i >> 7;                 // 128 float4 per row
    const int d = (i & 127) << 2;
    const int k = idx[n];

    float4 q  = *(const float4*)(E + (size_t)k * DDIM + d);
    float4 z  = *(const float4*)(Zr + base);
    float4 zi = *(const float4*)(Zi + base);
    *(float4*)(out + base) = q;
    *(float4*)(out + (size_t)NROWS * DDIM + base) = zi;

    const float dx = q.x - z.x, dy = q.y - z.y, dz = q.z - z.z, dw = q.w - z.w;
    float s = dx * dx + dy * dy + dz * dz + dw * dw;

    #pragma unroll
    for (int off = 32; off; off >>= 1) s += __shfl_down(s, off, 64);
    __shared__ float wred[4];
    const int lane = threadIdx.x & 63, wv = threadIdx.x >> 6;
    if (lane == 0) wred[wv] = s;
    __syncthreads();
    if (threadIdx.x == 0)
        partials[blockIdx.x] = wred[0] + wred[1] + wred[2] + wred[3];
}

// --------------------- K4: deterministic loss reduction ---------------------
__global__ void finalize_kernel(const float* __restrict__ partials,
                                float* __restrict__ out_loss) {
    __shared__ double red[256];
    double s = 0.0;
    for (int i = threadIdx.x; i < 16384; i += 256) s += (double)partials[i];
    red[threadIdx.x] = s;
    __syncthreads();
    for (int off = 128; off; off >>= 1) {
        if (threadIdx.x < off) red[threadIdx.x] += red[threadIdx.x + off];
        __syncthreads();
    }
    if (threadIdx.x == 0)
        *out_loss = (float)(1.25 * red[0] / 16777216.0);
}

extern "C" void kernel_launch(void* const* d_in, const int* in_sizes, int n_in,
                              void* d_out, int out_size, void* d_ws, size_t ws_size,
                              hipStream_t stream) {
    const float* z_real = (const float*)d_in[0];
    const float* z_imag = (const float*)d_in[1];
    const float* emb    = (const float*)d_in[2];
    float* out = (float*)d_out;

    // ws layout: h[4096] f32 @0 | idx[32768] i32 @16384 | partials[16384] f32 @147456
    float* h        = (float*)d_ws;
    int*   idx      = (int*)((char*)d_ws + 16384);
    float* partials = (float*)((char*)d_ws + 16384 + 131072);

    enorm_kernel<<<KCODES / 4, 256, 0, stream>>>(emb, h);
    argmin_kernel<<<NROWS / TM, 256, 0, stream>>>(z_real, emb, h, idx);
    gather_kernel<<<(NROWS * DDIM / 4) / 256, 256, 0, stream>>>(
        z_real, z_imag, emb, idx, out, partials);
    finalize_kernel<<<1, 256, 0, stream>>>(partials, out + (size_t)2 * NROWS * DDIM);
}

// Round 2
// 648.202 us; speedup vs baseline: 3.6716x; 3.6716x over previous
//
#include <hip/hip_runtime.h>

// VQ nearest-code search + gather + loss, MFMA split-bf16 edition.
// z_real [32,1024,512] f32, z_imag same, embedding [4096,512] f32.
// N=32768 rows, D=512, K=4096.
// Outputs (flat f32): quantized (16777216) | z_imag (16777216) | loss (1).
//
// Distance argmin: s_k = 0.5||e_k||^2 - x.e_k. The dot is computed with
// 3-pass split-bf16 MFMA (hi*hi + hi*lo + lo*hi), error ~4e-5 vs typical
// min-gap ~8. Scratch for the bf16 splits lives INSIDE d_out (region is
// consumed by the gemm, then overwritten by the gather epilogue).

#define NROWS 32768
#define DDIM  512
#define KCODES 4096
#define BM 128
#define BN 128
#define BK 32
#define KSPLIT 4
#define KPER (KCODES / KSPLIT)   // 1024 codes per k-split block

typedef short s16x8 __attribute__((ext_vector_type(8)));
typedef float f32x4 __attribute__((ext_vector_type(4)));
typedef unsigned long long u64;
typedef unsigned short u16;
typedef unsigned int u32;

__device__ __forceinline__ void glds16(const void* g, void* l) {
    __builtin_amdgcn_global_load_lds(
        (const __attribute__((address_space(1))) void*)g,
        (__attribute__((address_space(3))) void*)l, 16, 0, 0);
}

// float -> bf16 bits (RNE) + the value it rounds back to. Even if rounding
// differs slightly from HW, lo = bf16(x - hi) compensates (self-correcting).
__device__ __forceinline__ u16 f2bf(float x, float& back) {
    u32 b = __float_as_uint(x);
    u32 r = (b + 0x7fffu + ((b >> 16) & 1u)) >> 16;
    back = __uint_as_float(r << 16);
    return (u16)r;
}

// ------------------- K0: split fp32 -> bf16 hi/lo pair ----------------------
__global__ __launch_bounds__(256) void split_kernel(
    const float* __restrict__ src, u16* __restrict__ hi, u16* __restrict__ lo) {
    const size_t i = ((size_t)blockIdx.x * 256 + threadIdx.x) * 4;
    float4 v = *(const float4*)(src + i);
    ushort4 hv, lv;
    float bx, by, bz, bw;
    hv.x = f2bf(v.x, bx); hv.y = f2bf(v.y, by);
    hv.z = f2bf(v.z, bz); hv.w = f2bf(v.w, bw);
    float d;
    lv.x = f2bf(v.x - bx, d); lv.y = f2bf(v.y - by, d);
    lv.z = f2bf(v.z - bz, d); lv.w = f2bf(v.w - bw, d);
    *(ushort4*)(hi + i) = hv;
    *(ushort4*)(lo + i) = lv;
}

// ------------------------- K1: h[k] = 0.5*||e_k||^2 -------------------------
__global__ void enorm_kernel(const float* __restrict__ E, float* __restrict__ h) {
    const int k = blockIdx.x * 4 + (threadIdx.x >> 6);
    const int lane = threadIdx.x & 63;
    const float* row = E + (size_t)k * DDIM;
    float s = 0.f;
    #pragma unroll
    for (int d = 0; d < DDIM / 64; ++d) {
        float v = row[lane + d * 64];
        s += v * v;
    }
    #pragma unroll
    for (int off = 32; off; off >>= 1) s += __shfl_down(s, off, 64);
    if (lane == 0) h[k] = 0.5f * s;
}

// ------------- K2: MFMA score GEMM + fused running argmin -------------------
// grid = 256 row-blocks x 4 k-splits. Block: 256 thr = 4 waves (2x2),
// wave computes 64x64 of the 128x128 score tile via 4x4 16x16x32 MFMAs,
// 3 MFMA passes (hh, hl, lh) per fragment pair into one f32 accumulator.
__global__ __launch_bounds__(256, 2) void gemm_argmin_kernel(
    const u16* __restrict__ Xhi, const u16* __restrict__ Xlo,
    const u16* __restrict__ Ehi, const u16* __restrict__ Elo,
    const float* __restrict__ h, u64* __restrict__ packed) {
    __shared__ __align__(16) u16 smem[4 * BM * BK];   // Ahi|Alo|Bhi|Blo = 32 KB
    __shared__ u64 red[BM][2];

    const int t = threadIdx.x;
    const int lane = t & 63;
    const int wid = t >> 6;
    const int wr = wid >> 1, wc = wid & 1;
    const int bx = blockIdx.x & 255;
    const int ks = blockIdx.x >> 8;
    const size_t rowBase = (size_t)bx * BM;
    const int kBase = ks * KPER;

    u16* const buf0 = smem;                 // A hi
    u16* const buf1 = smem + BM * BK;       // A lo
    u16* const buf2 = smem + 2 * BM * BK;   // B hi
    u16* const buf3 = smem + 3 * BM * BK;   // B lo
    // wave wid stages buffer wid (wave-uniform LDS base, lane*16B dest)
    const u16* gsrc = (wid == 0) ? Xhi : (wid == 1) ? Xlo : (wid == 2) ? Ehi : Elo;
    u16* const ldsbuf = (wid == 0) ? buf0 : (wid == 1) ? buf1 : (wid == 2) ? buf2 : buf3;
    const int lrow = lane >> 2;          // row within 16-row segment
    const int lcol = (lane & 3) * 8;     // bf16-element offset (16 B)

    const int c = lane & 15, q = lane >> 4;

    float best[16];
    u32 besti[16];
    #pragma unroll
    for (int i = 0; i < 16; ++i) { best[i] = 3.4e38f; besti[i] = 0; }

    for (int kt = 0; kt < KPER; kt += BN) {
        f32x4 acc[4][4];
        #pragma unroll
        for (int i = 0; i < 4; ++i)
            #pragma unroll
            for (int j = 0; j < 4; ++j) acc[i][j] = f32x4{0.f, 0.f, 0.f, 0.f};

        const size_t gRow = (wid < 2) ? rowBase : (size_t)(kBase + kt);

        for (int d0 = 0; d0 < DDIM; d0 += BK) {
            __syncthreads();   // previous k-step's LDS reads done
            #pragma unroll
            for (int s = 0; s < 8; ++s) {
                const u16* g = gsrc + (gRow + s * 16 + lrow) * DDIM + d0 + lcol;
                glds16(g, ldsbuf + s * 16 * BK);
            }
            __syncthreads();   // all 4 buffers staged (vmcnt(0) implied)
            s16x8 ah[4], al[4], bh[4], bl[4];
            #pragma unroll
            for (int i = 0; i < 4; ++i) {
                const int m = wr * 64 + i * 16 + c;
                const int n = wc * 64 + i * 16 + c;
                ah[i] = *(const s16x8*)(buf0 + m * BK + q * 8);
                al[i] = *(const s16x8*)(buf1 + m * BK + q * 8);
                bh[i] = *(const s16x8*)(buf2 + n * BK + q * 8);
                bl[i] = *(const s16x8*)(buf3 + n * BK + q * 8);
            }
            #pragma unroll
            for (int i = 0; i < 4; ++i)
                #pragma unroll
                for (int j = 0; j < 4; ++j) {
                    acc[i][j] = __builtin_amdgcn_mfma_f32_16x16x32_bf16(ah[i], bh[j], acc[i][j], 0, 0, 0);
                    acc[i][j] = __builtin_amdgcn_mfma_f32_16x16x32_bf16(ah[i], bl[j], acc[i][j], 0, 0, 0);
                    acc[i][j] = __builtin_amdgcn_mfma_f32_16x16x32_bf16(al[i], bh[j], acc[i][j], 0, 0, 0);
                }
        }
        // fold h, update running argmin. cols ascend (kt, then j) => strict '<'
        // keeps lowest index per lane; cross-lane ties resolved in packed min.
        #pragma unroll
        for (int j = 0; j < 4; ++j) {
            const int col = kBase + kt + wc * 64 + j * 16 + c;
            const float hv = h[col];
            #pragma unroll
            for (int i = 0; i < 4; ++i)
                #pragma unroll
                for (int r = 0; r < 4; ++r) {
                    const float s = hv - acc[i][j][r];
                    const int slot = i * 4 + r;
                    if (s < best[slot]) { best[slot] = s; besti[slot] = (u32)col; }
                }
        }
    }

    // pack (score,idx); min over the 16 lanes of each quad (same rows)
    u64 p[16];
    #pragma unroll
    for (int i = 0; i < 16; ++i) {
        u32 ub = __float_as_uint(best[i]);
        ub = (ub & 0x80000000u) ? ~ub : (ub | 0x80000000u);
        p[i] = ((u64)ub << 32) | (u64)besti[i];
    }
    #pragma unroll
    for (int m = 1; m < 16; m <<= 1)
        #pragma unroll
        for (int i = 0; i < 16; ++i) {
            u64 o = __shfl_xor(p[i], m, 64);
            if (o < p[i]) p[i] = o;
        }
    if (c == 0) {
        #pragma unroll
        for (int i = 0; i < 16; ++i) {
            const int row = wr * 64 + (i >> 2) * 16 + q * 4 + (i & 3);
            red[row][wc] = p[i];
        }
    }
    __syncthreads();
    if (t < BM) {
        u64 a = red[t][0], b = red[t][1];
        packed[(rowBase + t) * KSPLIT + ks] = a < b ? a : b;
    }
}

// ----------------- K3: merge 4 k-split results -> final idx -----------------
__global__ void merge_kernel(const u64* __restrict__ packed, int* __restrict__ idx) {
    const int n = blockIdx.x * 256 + threadIdx.x;
    u64 m = packed[(size_t)n * 4];
    #pragma unroll
    for (int s = 1; s < 4; ++s) {
        u64 v = packed[(size_t)n * 4 + s];
        if (v < m) m = v;
    }
    idx[n] = (int)(u32)m;
}

// ---------- K4: gather quantized, copy z_imag, per-block loss partial -------
__global__ __launch_bounds__(256) void gather_kernel(
    const float* __restrict__ Zr, const float* __restrict__ Zi,
    const float* __restrict__ E, const int* __restrict__ idx,
    float* __restrict__ out, float* __restrict__ partials) {
    const int i = blockIdx.x * 256 + threadIdx.x;   // float4 index
    const size_t base = (size_t)i * 4;
    const int n = i >> 7;                 // 128 float4 per row
    const int d = (i & 127) << 2;
    const int k = idx[n];

    float4 qv = *(const float4*)(E + (size_t)k * DDIM + d);
    float4 z  = *(const float4*)(Zr + base);
    float4 zi = *(const float4*)(Zi + base);
    *(float4*)(out + base) = qv;
    *(float4*)(out + (size_t)NROWS * DDIM + base) = zi;

    const float dx = qv.x - z.x, dy = qv.y - z.y, dz = qv.z - z.z, dw = qv.w - z.w;
    float s = dx * dx + dy * dy + dz * dz + dw * dw;

    #pragma unroll
    for (int off = 32; off; off >>= 1) s += __shfl_down(s, off, 64);
    __shared__ float wred[4];
    const int lane = threadIdx.x & 63, wv = threadIdx.x >> 6;
    if (lane == 0) wred[wv] = s;
    __syncthreads();
    if (threadIdx.x == 0)
        partials[blockIdx.x] = wred[0] + wred[1] + wred[2] + wred[3];
}

// --------------------- K5: deterministic loss reduction ---------------------
__global__ void finalize_kernel(const float* __restrict__ partials,
                                float* __restrict__ out_loss) {
    __shared__ double red[256];
    double s = 0.0;
    for (int i = threadIdx.x; i < 16384; i += 256) s += (double)partials[i];
    red[threadIdx.x] = s;
    __syncthreads();
    for (int off = 128; off; off >>= 1) {
        if (threadIdx.x < off) red[threadIdx.x] += red[threadIdx.x + off];
        __syncthreads();
    }
    if (threadIdx.x == 0)
        *out_loss = (float)(1.25 * red[0] / 16777216.0);
}

extern "C" void kernel_launch(void* const* d_in, const int* in_sizes, int n_in,
                              void* d_out, int out_size, void* d_ws, size_t ws_size,
                              hipStream_t stream) {
    const float* z_real = (const float*)d_in[0];
    const float* z_imag = (const float*)d_in[1];
    const float* emb    = (const float*)d_in[2];
    float* out = (float*)d_out;
    char* outc = (char*)d_out;

    // Scratch INSIDE d_out (consumed before the gather overwrites it):
    //   region1 (quantized, 64 MB): Xhi 32 MB | Xlo 32 MB
    //   region2 (z_imag, 64 MB):    Ehi 4 MB | Elo 4 MB | h 16 KB | packed 1 MB
    u16* Xhi = (u16*)outc;
    u16* Xlo = (u16*)(outc + 33554432);
    char* reg2 = outc + 67108864;
    u16* Ehi = (u16*)reg2;
    u16* Elo = (u16*)(reg2 + 4194304);
    float* h = (float*)(reg2 + 8388608);
    u64* packed = (u64*)(reg2 + 8388608 + 16384);
    // ws: idx 128 KB | partials 64 KB  (196 KB total)
    int*   idx      = (int*)d_ws;
    float* partials = (float*)((char*)d_ws + 131072);

    split_kernel<<<16384, 256, 0, stream>>>(z_real, Xhi, Xlo);
    split_kernel<<<2048, 256, 0, stream>>>(emb, Ehi, Elo);
    enorm_kernel<<<KCODES / 4, 256, 0, stream>>>(emb, h);
    gemm_argmin_kernel<<<256 * KSPLIT, 256, 0, stream>>>(Xhi, Xlo, Ehi, Elo, h, packed);
    merge_kernel<<<NROWS / 256, 256, 0, stream>>>(packed, idx);
    gather_kernel<<<(NROWS * DDIM / 4) / 256, 256, 0, stream>>>(
        z_real, z_imag, emb, idx, out, partials);
    finalize_kernel<<<1, 256, 0, stream>>>(partials, out + (size_t)2 * NROWS * DDIM);
}